// Round 4
// baseline (409.807 us; speedup 1.0000x reference)
//
#include <hip/hip_runtime.h>

#define N_NODES 10000
#define E_EDGES 150000
#define KNB     15

// ---------------------------------------------------------------------------
// CSR build: count -> scan(+maskv, single pass) -> fill
// ---------------------------------------------------------------------------
__global__ void count_kernel(const int* __restrict__ idxs, int* __restrict__ cnt, int e) {
    int i = blockIdx.x * blockDim.x + threadIdx.x;
    if (i < e) atomicAdd(&cnt[idxs[i]], 1);
}

__global__ __launch_bounds__(1024)
void scan_kernel(const int* __restrict__ cnt, int* __restrict__ eoff,
                 float* __restrict__ maskv, int n) {
    __shared__ int lds[1024];
    int t = threadIdx.x;
    int base = t * 10;
    int v[10]; int s = 0;
#pragma unroll
    for (int q = 0; q < 10; ++q) {
        int i = base + q;
        v[q] = (i < n) ? cnt[i] : 0;
        s += v[q];
    }
    lds[t] = s;
    __syncthreads();
    for (int off = 1; off < 1024; off <<= 1) {
        int tv = (t >= off) ? lds[t - off] : 0;
        __syncthreads();
        lds[t] += tv;
        __syncthreads();
    }
    int ex = lds[t] - s;   // exclusive prefix of this thread's chunk
#pragma unroll
    for (int q = 0; q < 10; ++q) {
        int i = base + q;
        if (i < n) {
            eoff[i]  = ex;
            maskv[i] = (v[q] > 0) ? 1.f : 0.f;
            ex += v[q];
        }
    }
}

__global__ void fill_kernel(const int* __restrict__ idxs, const float* __restrict__ ea,
                            const int* __restrict__ eoff, int* __restrict__ fill,
                            float* __restrict__ eas, int e) {
    int i = blockIdx.x * blockDim.x + threadIdx.x;
    if (i < e) {
        int s = idxs[i];
        int p = atomicAdd(&fill[s], 1);
        eas[eoff[s] + p] = ea[i];
    }
}

// ---------------------------------------------------------------------------
// gemm_tile (MR=2 path) — used only by fold_kernel (weight-space folds)
// ---------------------------------------------------------------------------
template <int MR> struct AVecT;
template <> struct AVecT<4> { using T = float4; };
template <> struct AVecT<2> { using T = float2; };

template <int MR, bool RELU>
__device__ __forceinline__
void gemm_tile(const float* __restrict__ A, int K,
               const float* __restrict__ Blo, const float* __restrict__ Bhi, int ldB,
               float* __restrict__ C, int ldC, int M,
               int rowBlk, int colBlk) {
    constexpr int TM  = MR * 16;
    constexpr int PAD = (MR == 4) ? 4 : 2;
    using AVec = typename AVecT<MR>::T;
    __shared__ float As[16][TM + PAD];
    __shared__ float Bs[16][64];

    int tid = threadIdx.x;
    int tn  = tid & 15, tm = tid >> 4;
    int arow, acB;
    if (MR == 4) { arow = tid >> 2; acB = (tid & 3) << 2; }
    else         { arow = tid >> 3; acB = (tid & 7) << 1; }
    int brow = tid >> 4, bcol = (tid & 15) << 2;
    int rowBase = rowBlk * TM, colBase = colBlk * 64;

    bool half = (Bhi != nullptr) && (colBase >= 128);
    const float* B = half ? Bhi : Blo;
    int bj = colBase - (half ? 128 : 0) + bcol;

    AVec av; float4 bv;
    auto loadA = [&](int k0, AVec& dst) {
        int gr = rowBase + arow;
        if (gr < M) dst = *(const AVec*)(A + (size_t)gr * K + k0 + acB);
        else {
            if (MR == 4) { float4* p = (float4*)&dst; p->x = p->y = p->z = p->w = 0.f; }
            else         { float2* p = (float2*)&dst; p->x = p->y = 0.f; }
        }
    };
    auto loadB = [&](int k0, float4& dst) {
        dst = *(const float4*)(B + (size_t)(k0 + brow) * ldB + bj);
    };
    loadA(0, av); loadB(0, bv);

    float acc[MR][4] = {};
    for (int k0 = 0; k0 < K; k0 += 16) {
        __syncthreads();
        if (MR == 2) {
            float2 a2 = *(float2*)&av;
            As[acB + 0][arow] = a2.x; As[acB + 1][arow] = a2.y;
        }
        *(float4*)&Bs[brow][bcol] = bv;
        __syncthreads();
        if (k0 + 16 < K) { loadA(k0 + 16, av); loadB(k0 + 16, bv); }
#pragma unroll
        for (int k = 0; k < 16; ++k) {
            float4 b = *(const float4*)&Bs[k][tn << 2];
            float2 a = *(const float2*)&As[k][tm << 1];
            acc[0][0] = fmaf(a.x, b.x, acc[0][0]); acc[0][1] = fmaf(a.x, b.y, acc[0][1]);
            acc[0][2] = fmaf(a.x, b.z, acc[0][2]); acc[0][3] = fmaf(a.x, b.w, acc[0][3]);
            acc[1][0] = fmaf(a.y, b.x, acc[1][0]); acc[1][1] = fmaf(a.y, b.y, acc[1][1]);
            acc[1][2] = fmaf(a.y, b.z, acc[1][2]); acc[1][3] = fmaf(a.y, b.w, acc[1][3]);
        }
    }
#pragma unroll
    for (int i = 0; i < MR; ++i) {
        int row = rowBase + tm * MR + i;
        if (row >= M) continue;
#pragma unroll
        for (int j = 0; j < 4; ++j) {
            int gcol = colBase + (tn << 2) + j;
            float v = acc[i][j];
            if (RELU) v = fmaxf(v, 0.f);
            C[(size_t)row * ldC + gcol] = v;
        }
    }
}

// ---------------------------------------------------------------------------
// One-launch weight folds (same as R3, validated):
//  [0,8):   M1 = mw2 @ nw1[784:]            (K=784)
//  [8,16):  M2 = m2w2 @ n2w1[128:]          (K=128)
//  [16,32): WH = nw2 @ [m2w1[:128] | n2w1[:128]]   (128x256)
//  [32,40): v1, v2, bu2(+m2b1), bx2(+n2b1)
// ---------------------------------------------------------------------------
__global__ __launch_bounds__(256)
void fold_kernel(const float* __restrict__ mw2, const float* __restrict__ mb2,
                 const float* __restrict__ nw1, const float* __restrict__ nb2,
                 const float* __restrict__ nw2,
                 const float* __restrict__ m2w1, const float* __restrict__ m2b1,
                 const float* __restrict__ m2w2, const float* __restrict__ m2b2,
                 const float* __restrict__ n2w1, const float* __restrict__ n2b1,
                 float* __restrict__ M1, float* __restrict__ M2, float* __restrict__ WH,
                 float* __restrict__ v1, float* __restrict__ v2,
                 float* __restrict__ bu2, float* __restrict__ bx2) {
    int b = blockIdx.x;
    if (b < 8) {
        gemm_tile<2, false>(mw2, 784, nw1 + 784 * 128, nullptr, 128,
                            M1, 128, 128, b >> 1, b & 1);
    } else if (b < 16) {
        int t = b - 8;
        gemm_tile<2, false>(m2w2, 128, n2w1 + 128 * 128, nullptr, 128,
                            M2, 128, 128, t >> 1, t & 1);
    } else if (b < 32) {
        int t = b - 16;
        gemm_tile<2, false>(nw2, 128, m2w1, n2w1, 128,
                            WH, 256, 128, t >> 2, t & 3);
    } else {
        __shared__ float red[256];
        int t  = (b - 32) >> 1;
        int j  = ((b - 32) & 1) * 64 + (threadIdx.x & 63);
        int kq = threadIdx.x >> 6;
        const float* bvec; const float* Bv; const float* add; float* out; int Kv;
        if (t == 0)      { bvec = mb2;  Bv = nw1 + 784 * 128;  add = nullptr; out = v1;  Kv = 784; }
        else if (t == 1) { bvec = m2b2; Bv = n2w1 + 128 * 128; add = nullptr; out = v2;  Kv = 128; }
        else if (t == 2) { bvec = nb2;  Bv = m2w1;             add = m2b1;    out = bu2; Kv = 128; }
        else             { bvec = nb2;  Bv = n2w1;             add = n2b1;    out = bx2; Kv = 128; }
        float acc = 0.f;
        for (int k = kq; k < Kv; k += 4) acc = fmaf(bvec[k], Bv[k * 128 + j], acc);
        red[threadIdx.x] = acc;
        __syncthreads();
        if (threadIdx.x < 64) {
            float tot = red[threadIdx.x] + red[threadIdx.x + 64] +
                        red[threadIdx.x + 128] + red[threadIdx.x + 192];
            out[j] = tot + (add ? add[j] : 0.f);
        }
    }
}

// ---------------------------------------------------------------------------
// GEMM-A: UX = [ x@mw1[:784]+mb1 | x@nw1[:784]+nb1+maskv*v1 ]
// A direct from global (lane-broadcast, L1-served); LDS only for B (dbuf).
// grid: 628 linear blocks: rowBlk = bid>>2, colBlk = bid&3 (L2 locality on x).
// ---------------------------------------------------------------------------
__global__ __launch_bounds__(256)
void gemm784_kernel(const float* __restrict__ A,
                    const float* __restrict__ Blo, const float* __restrict__ Bhi,
                    const float* __restrict__ biasLo, const float* __restrict__ biasHi,
                    const float* __restrict__ vhi, const float* __restrict__ rowmask,
                    float* __restrict__ C, int M) {
    __shared__ float Bs[2][16][64];
    int bid = blockIdx.x;
    int rowBlk = bid >> 2, colBlk = bid & 3;
    int tid = threadIdx.x, tm = tid >> 4, tn = tid & 15;
    int rowBase = rowBlk * 64, colBase = colBlk * 64;
    bool half = colBase >= 128;
    const float* B    = half ? Bhi : Blo;
    const float* bias = half ? biasHi : biasLo;
    int bj   = (colBase & 127) + (tn << 2);
    int brow = tid >> 4;

    const float* ap[4];
#pragma unroll
    for (int i = 0; i < 4; ++i) {
        int r = rowBase + tm * 4 + i;
        if (r > M - 1) r = M - 1;           // clamp; stores guarded
        ap[i] = A + (size_t)r * 784;
    }

    float4 bv = *(const float4*)(B + (size_t)brow * 128 + bj);
    *(float4*)&Bs[0][brow][tn << 2] = bv;
    bv = *(const float4*)(B + (size_t)(16 + brow) * 128 + bj);
    __syncthreads();

    float acc[4][4] = {};
    for (int k0 = 0; k0 < 784; k0 += 16) {
        int buf = (k0 >> 4) & 1;
        if (k0 + 16 < 784) {
            *(float4*)&Bs[buf ^ 1][brow][tn << 2] = bv;
            if (k0 + 32 < 784) bv = *(const float4*)(B + (size_t)(k0 + 32 + brow) * 128 + bj);
        }
        // A fragments for this tile: 16 x float4 (lane-broadcast global loads)
        float4 aq[4][4];
#pragma unroll
        for (int q = 0; q < 4; ++q)
#pragma unroll
            for (int i = 0; i < 4; ++i)
                aq[q][i] = *(const float4*)(ap[i] + k0 + (q << 2));
#pragma unroll
        for (int q = 0; q < 4; ++q) {
#pragma unroll
            for (int kk = 0; kk < 4; ++kk) {
                float4 b = *(const float4*)&Bs[buf][(q << 2) | kk][tn << 2];
                float a0 = ((const float*)&aq[q][0])[kk];
                float a1 = ((const float*)&aq[q][1])[kk];
                float a2 = ((const float*)&aq[q][2])[kk];
                float a3 = ((const float*)&aq[q][3])[kk];
                acc[0][0] = fmaf(a0, b.x, acc[0][0]); acc[0][1] = fmaf(a0, b.y, acc[0][1]);
                acc[0][2] = fmaf(a0, b.z, acc[0][2]); acc[0][3] = fmaf(a0, b.w, acc[0][3]);
                acc[1][0] = fmaf(a1, b.x, acc[1][0]); acc[1][1] = fmaf(a1, b.y, acc[1][1]);
                acc[1][2] = fmaf(a1, b.z, acc[1][2]); acc[1][3] = fmaf(a1, b.w, acc[1][3]);
                acc[2][0] = fmaf(a2, b.x, acc[2][0]); acc[2][1] = fmaf(a2, b.y, acc[2][1]);
                acc[2][2] = fmaf(a2, b.z, acc[2][2]); acc[2][3] = fmaf(a2, b.w, acc[2][3]);
                acc[3][0] = fmaf(a3, b.x, acc[3][0]); acc[3][1] = fmaf(a3, b.y, acc[3][1]);
                acc[3][2] = fmaf(a3, b.z, acc[3][2]); acc[3][3] = fmaf(a3, b.w, acc[3][3]);
            }
        }
        __syncthreads();
    }

#pragma unroll
    for (int i = 0; i < 4; ++i) {
        int row = rowBase + tm * 4 + i;
        if (row >= M) continue;
#pragma unroll
        for (int j = 0; j < 4; ++j) {
            int gcol = colBase + (tn << 2) + j;
            int cj   = gcol & 127;
            float v = acc[i][j] + bias[cj];
            if (half) v = fmaf(rowmask[row], vhi[cj], v);
            C[(size_t)row * 256 + gcol] = v;
        }
    }
}

// ---------------------------------------------------------------------------
// fused_mid: per 32-row tile (grid 626: rowBlk=bid>>1, y=bid&1):
//   phase0: mhT[d][m] = mean_e relu(UX[u][d] + ea*w[d]);  rmask
//   phase1: ts[32][128] = relu(UX[xn] + mhT @ M1)
//   phase2: UX2[:, y*128..] = ts @ WH[:, y*128..] + bias (+rm*v2 on y=1)
// ---------------------------------------------------------------------------
__global__ __launch_bounds__(256)
void fused_mid_kernel(const float* __restrict__ UX, const float* __restrict__ wlast,
                      const float* __restrict__ eas, const int* __restrict__ eoff,
                      const int* __restrict__ cnt,
                      const float* __restrict__ Mmat, const float* __restrict__ WH,
                      const float* __restrict__ bu2, const float* __restrict__ bx2,
                      const float* __restrict__ v2,
                      float* __restrict__ UX2, int M) {
    __shared__ float mhT[128][36];   // [k][m], stride 36 floats = 144 B (16B-aligned)
    __shared__ float ts[32][132];    // [m][k]
    __shared__ float Bs[16][132];
    __shared__ float rmask[32];
    int bid = blockIdx.x;
    int rowBase = (bid >> 1) * 32, yhalf = bid & 1;
    int tid = threadIdx.x;

    // ---- phase 0: per-node message mean ----
    {
        int d = tid & 127, sub = tid >> 7;
        float w = wlast[d];
        for (int it = 0; it < 16; ++it) {
            int n  = rowBase + it * 2 + sub;
            int nc = (n < M) ? n : M - 1;
            int c = cnt[nc], base = eoff[nc];
            float uu = UX[(size_t)nc * 256 + d];
            float s = 0.f;
            for (int e = 0; e < c; ++e) s += fmaxf(fmaf(eas[base + e], w, uu), 0.f);
            mhT[d][it * 2 + sub] = (c > 0) ? s / (float)c : 0.f;
            if (d == 0) rmask[it * 2 + sub] = (c > 0) ? 1.f : 0.f;
        }
    }
    __syncthreads();

    int tm = tid >> 5, tn = tid & 31;

    // ---- phase 1: ts = relu(xn + mhT @ Mmat) ----
    {
        float acc[4][4] = {};
        for (int k0 = 0; k0 < 128; k0 += 16) {
#pragma unroll
            for (int t2 = 0; t2 < 2; ++t2) {
                int f2 = (tid << 1) | t2;
                int kr = f2 >> 5, c4 = (f2 & 31) << 2;
                *(float4*)&Bs[kr][c4] = *(const float4*)(Mmat + (size_t)(k0 + kr) * 128 + c4);
            }
            __syncthreads();
#pragma unroll
            for (int k = 0; k < 16; ++k) {
                float4 a = *(const float4*)&mhT[k0 + k][tm << 2];
                float4 b = *(const float4*)&Bs[k][tn << 2];
                acc[0][0] = fmaf(a.x, b.x, acc[0][0]); acc[0][1] = fmaf(a.x, b.y, acc[0][1]);
                acc[0][2] = fmaf(a.x, b.z, acc[0][2]); acc[0][3] = fmaf(a.x, b.w, acc[0][3]);
                acc[1][0] = fmaf(a.y, b.x, acc[1][0]); acc[1][1] = fmaf(a.y, b.y, acc[1][1]);
                acc[1][2] = fmaf(a.y, b.z, acc[1][2]); acc[1][3] = fmaf(a.y, b.w, acc[1][3]);
                acc[2][0] = fmaf(a.z, b.x, acc[2][0]); acc[2][1] = fmaf(a.z, b.y, acc[2][1]);
                acc[2][2] = fmaf(a.z, b.z, acc[2][2]); acc[2][3] = fmaf(a.z, b.w, acc[2][3]);
                acc[3][0] = fmaf(a.w, b.x, acc[3][0]); acc[3][1] = fmaf(a.w, b.y, acc[3][1]);
                acc[3][2] = fmaf(a.w, b.z, acc[3][2]); acc[3][3] = fmaf(a.w, b.w, acc[3][3]);
            }
            __syncthreads();
        }
#pragma unroll
        for (int i = 0; i < 4; ++i) {
            int row = rowBase + (tm << 2) + i;
            int rc  = (row < M) ? row : M - 1;
#pragma unroll
            for (int j = 0; j < 4; ++j) {
                int col = (tn << 2) + j;
                float v = acc[i][j] + UX[(size_t)rc * 256 + 128 + col];
                ts[(tm << 2) + i][col] = fmaxf(v, 0.f);
            }
        }
    }

    // ---- phase 2: UX2 half = ts @ WH-half + bias ----
    {
        const float* Bmat = WH + yhalf * 128;
        const float* bias = yhalf ? bx2 : bu2;
        float acc[4][4] = {};
        for (int k0 = 0; k0 < 128; k0 += 16) {
#pragma unroll
            for (int t2 = 0; t2 < 2; ++t2) {
                int f2 = (tid << 1) | t2;
                int kr = f2 >> 5, c4 = (f2 & 31) << 2;
                *(float4*)&Bs[kr][c4] = *(const float4*)(Bmat + (size_t)(k0 + kr) * 256 + c4);
            }
            __syncthreads();   // also orders ts writes (phase1) before ts reads
#pragma unroll
            for (int k = 0; k < 16; ++k) {
                float a0 = ts[(tm << 2) + 0][k0 + k];
                float a1 = ts[(tm << 2) + 1][k0 + k];
                float a2 = ts[(tm << 2) + 2][k0 + k];
                float a3 = ts[(tm << 2) + 3][k0 + k];
                float4 b = *(const float4*)&Bs[k][tn << 2];
                acc[0][0] = fmaf(a0, b.x, acc[0][0]); acc[0][1] = fmaf(a0, b.y, acc[0][1]);
                acc[0][2] = fmaf(a0, b.z, acc[0][2]); acc[0][3] = fmaf(a0, b.w, acc[0][3]);
                acc[1][0] = fmaf(a1, b.x, acc[1][0]); acc[1][1] = fmaf(a1, b.y, acc[1][1]);
                acc[1][2] = fmaf(a1, b.z, acc[1][2]); acc[1][3] = fmaf(a1, b.w, acc[1][3]);
                acc[2][0] = fmaf(a2, b.x, acc[2][0]); acc[2][1] = fmaf(a2, b.y, acc[2][1]);
                acc[2][2] = fmaf(a2, b.z, acc[2][2]); acc[2][3] = fmaf(a2, b.w, acc[2][3]);
                acc[3][0] = fmaf(a3, b.x, acc[3][0]); acc[3][1] = fmaf(a3, b.y, acc[3][1]);
                acc[3][2] = fmaf(a3, b.z, acc[3][2]); acc[3][3] = fmaf(a3, b.w, acc[3][3]);
            }
            __syncthreads();
        }
#pragma unroll
        for (int i = 0; i < 4; ++i) {
            int row = rowBase + (tm << 2) + i;
            if (row >= M) continue;
            float rm = rmask[(tm << 2) + i];
#pragma unroll
            for (int j = 0; j < 4; ++j) {
                int col = (tn << 2) + j;
                float v = acc[i][j] + bias[col];
                if (yhalf) v = fmaf(rm, v2[col], v);
                UX2[(size_t)row * 256 + yhalf * 128 + col] = v;
            }
        }
    }
}

// ---------------------------------------------------------------------------
// fused_last: phase0 (msg mean on UX2-u) + z2 = relu(xn2 + mh@M2) + proj
// grid 313 blocks x 32 rows. proj via in-register partials + shuffle reduce.
// ---------------------------------------------------------------------------
__global__ __launch_bounds__(256)
void fused_last_kernel(const float* __restrict__ UX2, const float* __restrict__ wlast,
                       const float* __restrict__ eas, const int* __restrict__ eoff,
                       const int* __restrict__ cnt,
                       const float* __restrict__ Mmat,
                       const float* __restrict__ w2, const float* __restrict__ b2,
                       float* __restrict__ proj, int M) {
    __shared__ float mhT[128][36];
    __shared__ float Bs[16][132];
    int rowBase = blockIdx.x * 32;
    int tid = threadIdx.x;

    {
        int d = tid & 127, sub = tid >> 7;
        float w = wlast[d];
        for (int it = 0; it < 16; ++it) {
            int n  = rowBase + it * 2 + sub;
            int nc = (n < M) ? n : M - 1;
            int c = cnt[nc], base = eoff[nc];
            float uu = UX2[(size_t)nc * 256 + d];
            float s = 0.f;
            for (int e = 0; e < c; ++e) s += fmaxf(fmaf(eas[base + e], w, uu), 0.f);
            mhT[d][it * 2 + sub] = (c > 0) ? s / (float)c : 0.f;
        }
    }
    __syncthreads();

    int tm = tid >> 5, tn = tid & 31;
    float acc[4][4] = {};
    for (int k0 = 0; k0 < 128; k0 += 16) {
#pragma unroll
        for (int t2 = 0; t2 < 2; ++t2) {
            int f2 = (tid << 1) | t2;
            int kr = f2 >> 5, c4 = (f2 & 31) << 2;
            *(float4*)&Bs[kr][c4] = *(const float4*)(Mmat + (size_t)(k0 + kr) * 128 + c4);
        }
        __syncthreads();
#pragma unroll
        for (int k = 0; k < 16; ++k) {
            float4 a = *(const float4*)&mhT[k0 + k][tm << 2];
            float4 b = *(const float4*)&Bs[k][tn << 2];
            acc[0][0] = fmaf(a.x, b.x, acc[0][0]); acc[0][1] = fmaf(a.x, b.y, acc[0][1]);
            acc[0][2] = fmaf(a.x, b.z, acc[0][2]); acc[0][3] = fmaf(a.x, b.w, acc[0][3]);
            acc[1][0] = fmaf(a.y, b.x, acc[1][0]); acc[1][1] = fmaf(a.y, b.y, acc[1][1]);
            acc[1][2] = fmaf(a.y, b.z, acc[1][2]); acc[1][3] = fmaf(a.y, b.w, acc[1][3]);
            acc[2][0] = fmaf(a.z, b.x, acc[2][0]); acc[2][1] = fmaf(a.z, b.y, acc[2][1]);
            acc[2][2] = fmaf(a.z, b.z, acc[2][2]); acc[2][3] = fmaf(a.z, b.w, acc[2][3]);
            acc[3][0] = fmaf(a.w, b.x, acc[3][0]); acc[3][1] = fmaf(a.w, b.y, acc[3][1]);
            acc[3][2] = fmaf(a.w, b.z, acc[3][2]); acc[3][3] = fmaf(a.w, b.w, acc[3][3]);
        }
        __syncthreads();
    }

    // z2 + proj partials (t never materialized)
    float p0[4] = {}, p1[4] = {};
#pragma unroll
    for (int i = 0; i < 4; ++i) {
        int row = rowBase + (tm << 2) + i;
        int rc  = (row < M) ? row : M - 1;
#pragma unroll
        for (int j = 0; j < 4; ++j) {
            int col = (tn << 2) + j;
            float t = fmaxf(acc[i][j] + UX2[(size_t)rc * 256 + 128 + col], 0.f);
            p0[i] = fmaf(t, w2[col * 2],     p0[i]);
            p1[i] = fmaf(t, w2[col * 2 + 1], p1[i]);
        }
    }
    // reduce over tn (32 lanes within each half-wave; tm constant per half-wave)
#pragma unroll
    for (int i = 0; i < 4; ++i) {
        for (int off = 16; off > 0; off >>= 1) {
            p0[i] += __shfl_xor(p0[i], off, 64);
            p1[i] += __shfl_xor(p1[i], off, 64);
        }
    }
    if (tn == 0) {
#pragma unroll
        for (int i = 0; i < 4; ++i) {
            int row = rowBase + (tm << 2) + i;
            if (row < M) {
                proj[row * 2]     = p0[i] + b2[0];
                proj[row * 2 + 1] = p1[i] + b2[1];
            }
        }
    }
}

__global__ void dist_kernel(const float* __restrict__ proj, const int* __restrict__ idxs,
                            float* __restrict__ out, int e) {
    int i = blockIdx.x * blockDim.x + threadIdx.x;
    if (i >= e) return;
    int n = i / KNB;
    int m = idxs[i];
    float dx = proj[2 * n] - proj[2 * m];
    float dy = proj[2 * n + 1] - proj[2 * m + 1];
    out[i] = dx * dx + dy * dy;
}

// ---------------------------------------------------------------------------
extern "C" void kernel_launch(void* const* d_in, const int* in_sizes, int n_in,
                              void* d_out, int out_size, void* d_ws, size_t ws_size,
                              hipStream_t stream) {
    (void)in_sizes; (void)n_in; (void)out_size; (void)ws_size;
    const float* x    = (const float*)d_in[0];
    const float* eatt = (const float*)d_in[1];
    const int*   idxs = (const int*)d_in[2];
    const float* mw1  = (const float*)d_in[3];
    const float* mb1  = (const float*)d_in[4];
    const float* mw2  = (const float*)d_in[5];
    const float* mb2  = (const float*)d_in[6];
    const float* nw1  = (const float*)d_in[7];
    const float* nb1  = (const float*)d_in[8];
    const float* nw2  = (const float*)d_in[9];
    const float* nb2  = (const float*)d_in[10];
    const float* m2w1 = (const float*)d_in[11];
    const float* m2b1 = (const float*)d_in[12];
    const float* m2w2 = (const float*)d_in[13];
    const float* m2b2 = (const float*)d_in[14];
    const float* n2w1 = (const float*)d_in[15];
    const float* n2b1 = (const float*)d_in[16];
    const float* n2w2 = (const float*)d_in[17];
    const float* n2b2 = (const float*)d_in[18];
    float* out = (float*)d_out;

    float* fws   = (float*)d_ws;
    float* UX1   = fws;                   // 10000*256
    float* UX2   = fws + 2560000;         // 10000*256
    float* proj  = fws + 5120000;         // 10000*2
    float* maskv = fws + 5140000;         // 10000
    float* eas   = fws + 5150016;         // 150000
    float* M1    = fws + 5300016;         // 128*128
    float* M2    = fws + 5316400;         // 128*128
    float* WH    = fws + 5332784;         // 128*256
    float* v1    = fws + 5365552;         // 128
    float* v2    = fws + 5365680;         // 128
    float* bu2   = fws + 5365808;         // 128
    float* bx2   = fws + 5365936;         // 128
    int*   cnt   = (int*)(fws + 5366064);
    int*   fill  = cnt + N_NODES;
    int*   eoff  = fill + N_NODES;

    hipMemsetAsync(cnt, 0, 2 * N_NODES * sizeof(int), stream);   // cnt + fill

    int egrid = (E_EDGES + 255) / 256;
    count_kernel<<<egrid, 256, 0, stream>>>(idxs, cnt, E_EDGES);
    scan_kernel<<<1, 1024, 0, stream>>>(cnt, eoff, maskv, N_NODES);
    fill_kernel<<<egrid, 256, 0, stream>>>(idxs, eatt, eoff, fill, eas, E_EDGES);

    fold_kernel<<<40, 256, 0, stream>>>(mw2, mb2, nw1, nb2, nw2,
                                        m2w1, m2b1, m2w2, m2b2, n2w1, n2b1,
                                        M1, M2, WH, v1, v2, bu2, bx2);

    // UX1 = [ x@mw1+mb1 | x@nw1+nb1+maskv*v1 ]
    gemm784_kernel<<<628, 256, 0, stream>>>(x, mw1, nw1, mb1, nb1, v1, maskv,
                                            UX1, N_NODES);

    // layer 1 msg-mean + z1 + layer-2 input projection
    fused_mid_kernel<<<626, 256, 0, stream>>>(UX1, mw1 + 784 * 128, eas, eoff, cnt,
                                              M1, WH, bu2, bx2, v2, UX2, N_NODES);

    // layer 2 msg-mean + z2 + proj
    fused_last_kernel<<<313, 256, 0, stream>>>(UX2, m2w1 + 128 * 128, eas, eoff, cnt,
                                               M2, n2w2, n2b2, proj, N_NODES);

    dist_kernel<<<egrid, 256, 0, stream>>>(proj, idxs, out, E_EDGES);
}

// Round 5
// 377.666 us; speedup vs baseline: 1.0851x; 1.0851x over previous
//
#include <hip/hip_runtime.h>

#define N_NODES 10000
#define E_EDGES 150000
#define KNB     15

// ---------------------------------------------------------------------------
// CSR build: count -> scan(+maskv, single pass) -> fill
// ---------------------------------------------------------------------------
__global__ void count_kernel(const int* __restrict__ idxs, int* __restrict__ cnt, int e) {
    int i = blockIdx.x * blockDim.x + threadIdx.x;
    if (i < e) atomicAdd(&cnt[idxs[i]], 1);
}

__global__ __launch_bounds__(1024)
void scan_kernel(const int* __restrict__ cnt, int* __restrict__ eoff,
                 float* __restrict__ maskv, int n) {
    __shared__ int lds[1024];
    int t = threadIdx.x;
    int base = t * 10;
    int v[10]; int s = 0;
#pragma unroll
    for (int q = 0; q < 10; ++q) {
        int i = base + q;
        v[q] = (i < n) ? cnt[i] : 0;
        s += v[q];
    }
    lds[t] = s;
    __syncthreads();
    for (int off = 1; off < 1024; off <<= 1) {
        int tv = (t >= off) ? lds[t - off] : 0;
        __syncthreads();
        lds[t] += tv;
        __syncthreads();
    }
    int ex = lds[t] - s;
#pragma unroll
    for (int q = 0; q < 10; ++q) {
        int i = base + q;
        if (i < n) {
            eoff[i]  = ex;
            maskv[i] = (v[q] > 0) ? 1.f : 0.f;
            ex += v[q];
        }
    }
}

__global__ void fill_kernel(const int* __restrict__ idxs, const float* __restrict__ ea,
                            const int* __restrict__ eoff, int* __restrict__ fill,
                            float* __restrict__ eas, int e) {
    int i = blockIdx.x * blockDim.x + threadIdx.x;
    if (i < e) {
        int s = idxs[i];
        int p = atomicAdd(&fill[s], 1);
        eas[eoff[s] + p] = ea[i];
    }
}

// ---------------------------------------------------------------------------
// gemm_tile (MR=2) — used only by fold_kernel (weight-space folds)
// ---------------------------------------------------------------------------
__device__ __forceinline__
void gemm_tile2(const float* __restrict__ A, int K,
                const float* __restrict__ Blo, const float* __restrict__ Bhi, int ldB,
                float* __restrict__ C, int ldC, int M,
                int rowBlk, int colBlk) {
    __shared__ float As[16][34];
    __shared__ float Bs[16][64];
    int tid = threadIdx.x;
    int tn  = tid & 15, tm = tid >> 4;
    int arow = tid >> 3, acB = (tid & 7) << 1;
    int brow = tid >> 4, bcol = (tid & 15) << 2;
    int rowBase = rowBlk * 32, colBase = colBlk * 64;

    bool half = (Bhi != nullptr) && (colBase >= 128);
    const float* B = half ? Bhi : Blo;
    int bj = colBase - (half ? 128 : 0) + bcol;

    float2 av; float4 bv;
    auto loadA = [&](int k0, float2& dst) {
        int gr = rowBase + arow;
        if (gr < M) dst = *(const float2*)(A + (size_t)gr * K + k0 + acB);
        else { dst.x = dst.y = 0.f; }
    };
    auto loadB = [&](int k0, float4& dst) {
        dst = *(const float4*)(B + (size_t)(k0 + brow) * ldB + bj);
    };
    loadA(0, av); loadB(0, bv);

    float acc[2][4] = {};
    for (int k0 = 0; k0 < K; k0 += 16) {
        __syncthreads();
        As[acB + 0][arow] = av.x; As[acB + 1][arow] = av.y;
        *(float4*)&Bs[brow][bcol] = bv;
        __syncthreads();
        if (k0 + 16 < K) { loadA(k0 + 16, av); loadB(k0 + 16, bv); }
#pragma unroll
        for (int k = 0; k < 16; ++k) {
            float4 b = *(const float4*)&Bs[k][tn << 2];
            float2 a = *(const float2*)&As[k][tm << 1];
            acc[0][0] = fmaf(a.x, b.x, acc[0][0]); acc[0][1] = fmaf(a.x, b.y, acc[0][1]);
            acc[0][2] = fmaf(a.x, b.z, acc[0][2]); acc[0][3] = fmaf(a.x, b.w, acc[0][3]);
            acc[1][0] = fmaf(a.y, b.x, acc[1][0]); acc[1][1] = fmaf(a.y, b.y, acc[1][1]);
            acc[1][2] = fmaf(a.y, b.z, acc[1][2]); acc[1][3] = fmaf(a.y, b.w, acc[1][3]);
        }
    }
#pragma unroll
    for (int i = 0; i < 2; ++i) {
        int row = rowBase + tm * 2 + i;
        if (row >= M) continue;
#pragma unroll
        for (int j = 0; j < 4; ++j)
            C[(size_t)row * ldC + colBase + (tn << 2) + j] = acc[i][j];
    }
}

// ---------------------------------------------------------------------------
// One-launch weight folds:
//  [0,8):   M1 = mw2 @ nw1[784:]            (K=784)
//  [8,16):  M2 = m2w2 @ n2w1[128:]          (K=128)
//  [16,32): WH = nw2 @ [m2w1[:128] | n2w1[:128]]   (128x256)
//  [32,40): v1, v2, bu2(+m2b1), bx2(+n2b1)
// ---------------------------------------------------------------------------
__global__ __launch_bounds__(256)
void fold_kernel(const float* __restrict__ mw2, const float* __restrict__ mb2,
                 const float* __restrict__ nw1, const float* __restrict__ nb2,
                 const float* __restrict__ nw2,
                 const float* __restrict__ m2w1, const float* __restrict__ m2b1,
                 const float* __restrict__ m2w2, const float* __restrict__ m2b2,
                 const float* __restrict__ n2w1, const float* __restrict__ n2b1,
                 float* __restrict__ M1, float* __restrict__ M2, float* __restrict__ WH,
                 float* __restrict__ v1, float* __restrict__ v2,
                 float* __restrict__ bu2, float* __restrict__ bx2) {
    int b = blockIdx.x;
    if (b < 8) {
        gemm_tile2(mw2, 784, nw1 + 784 * 128, nullptr, 128, M1, 128, 128, b >> 1, b & 1);
    } else if (b < 16) {
        int t = b - 8;
        gemm_tile2(m2w2, 128, n2w1 + 128 * 128, nullptr, 128, M2, 128, 128, t >> 1, t & 1);
    } else if (b < 32) {
        int t = b - 16;
        gemm_tile2(nw2, 128, m2w1, n2w1, 128, WH, 256, 128, t >> 2, t & 3);
    } else {
        __shared__ float red[256];
        int t  = (b - 32) >> 1;
        int j  = ((b - 32) & 1) * 64 + (threadIdx.x & 63);
        int kq = threadIdx.x >> 6;
        const float* bvec; const float* Bv; const float* add; float* out; int Kv;
        if (t == 0)      { bvec = mb2;  Bv = nw1 + 784 * 128;  add = nullptr; out = v1;  Kv = 784; }
        else if (t == 1) { bvec = m2b2; Bv = n2w1 + 128 * 128; add = nullptr; out = v2;  Kv = 128; }
        else if (t == 2) { bvec = nb2;  Bv = m2w1;             add = m2b1;    out = bu2; Kv = 128; }
        else             { bvec = nb2;  Bv = n2w1;             add = n2b1;    out = bx2; Kv = 128; }
        float acc = 0.f;
        for (int k = kq; k < Kv; k += 4) acc = fmaf(bvec[k], Bv[k * 128 + j], acc);
        red[threadIdx.x] = acc;
        __syncthreads();
        if (threadIdx.x < 64) {
            float tot = red[threadIdx.x] + red[threadIdx.x + 64] +
                        red[threadIdx.x + 128] + red[threadIdx.x + 192];
            out[j] = tot + (add ? add[j] : 0.f);
        }
    }
}

// ---------------------------------------------------------------------------
// GEMM-A: UX = [ x@mw1[:784]+mb1 | x@nw1[:784]+nb1+maskv*v1 ]
// 128x128 tile, 8x8 micro (1 B LDS per FMA), A+B LDS dbuf, 1 barrier/tile.
// grid 158: rowBlk = bid>>1, colBlk = bid&1 (colBlk selects mw1 vs nw1).
// ---------------------------------------------------------------------------
__global__ __launch_bounds__(256)
void gemm784_kernel(const float* __restrict__ A,
                    const float* __restrict__ Blo, const float* __restrict__ Bhi,
                    const float* __restrict__ biasLo, const float* __restrict__ biasHi,
                    const float* __restrict__ vhi, const float* __restrict__ rowmask,
                    float* __restrict__ C, int M) {
    __shared__ float As[2][16][132];
    __shared__ float Bs[2][16][132];
    int bid = blockIdx.x;
    int rowBlk = bid >> 1, colBlk = bid & 1;
    int tid = threadIdx.x;
    int tm8 = (tid >> 4) << 3;            // 0..120 row offset
    int tn8 = (tid & 15) << 3;            // 0..120 col offset
    int rowBase = rowBlk * 128;
    const float* B    = colBlk ? Bhi : Blo;
    const float* bias = colBlk ? biasHi : biasLo;

    int arow = tid >> 1;                  // 0..127
    int aoff = (tid & 1) << 3;            // 0 or 8
    int gr = rowBase + arow; if (gr > M - 1) gr = M - 1;   // clamp, stores guarded
    const float* Ap = A + (size_t)gr * 784;
    int brow = tid >> 4;                  // 0..15
    int bcol = (tid & 15) << 3;           // 0..120

    float4 ar0, ar1, br0, br1;
    auto gload = [&](int k0) {
        ar0 = *(const float4*)(Ap + k0 + aoff);
        ar1 = *(const float4*)(Ap + k0 + aoff + 4);
        const float* Bp = B + (size_t)(k0 + brow) * 128 + bcol;
        br0 = *(const float4*)(Bp);
        br1 = *(const float4*)(Bp + 4);
    };
    auto sstore = [&](int buf) {
        As[buf][aoff + 0][arow] = ar0.x; As[buf][aoff + 1][arow] = ar0.y;
        As[buf][aoff + 2][arow] = ar0.z; As[buf][aoff + 3][arow] = ar0.w;
        As[buf][aoff + 4][arow] = ar1.x; As[buf][aoff + 5][arow] = ar1.y;
        As[buf][aoff + 6][arow] = ar1.z; As[buf][aoff + 7][arow] = ar1.w;
        *(float4*)&Bs[buf][brow][bcol]     = br0;
        *(float4*)&Bs[buf][brow][bcol + 4] = br1;
    };
    gload(0); sstore(0);

    float acc[8][8] = {};
    for (int t = 0; t < 49; ++t) {
        __syncthreads();
        if (t < 48) gload((t + 1) << 4);
        int buf = t & 1;
#pragma unroll
        for (int k = 0; k < 16; ++k) {
            float4 a0 = *(const float4*)&As[buf][k][tm8];
            float4 a1 = *(const float4*)&As[buf][k][tm8 + 4];
            float4 b0 = *(const float4*)&Bs[buf][k][tn8];
            float4 b1 = *(const float4*)&Bs[buf][k][tn8 + 4];
            float ar[8] = {a0.x, a0.y, a0.z, a0.w, a1.x, a1.y, a1.z, a1.w};
            float br[8] = {b0.x, b0.y, b0.z, b0.w, b1.x, b1.y, b1.z, b1.w};
#pragma unroll
            for (int i = 0; i < 8; ++i)
#pragma unroll
                for (int j = 0; j < 8; ++j)
                    acc[i][j] = fmaf(ar[i], br[j], acc[i][j]);
        }
        if (t < 48) sstore(buf ^ 1);
    }

#pragma unroll
    for (int i = 0; i < 8; ++i) {
        int row = rowBase + tm8 + i;
        if (row >= M) continue;
        float rm = colBlk ? rowmask[row] : 0.f;
        float4 o0, o1;
        float* po0 = (float*)&o0; float* po1 = (float*)&o1;
#pragma unroll
        for (int j = 0; j < 4; ++j) {
            int cj0 = tn8 + j, cj1 = tn8 + 4 + j;
            float v0 = acc[i][j] + bias[cj0];
            float v1s = acc[i][4 + j] + bias[cj1];
            if (colBlk) { v0 = fmaf(rm, vhi[cj0], v0); v1s = fmaf(rm, vhi[cj1], v1s); }
            po0[j] = v0; po1[j] = v1s;
        }
        float* Crow = C + (size_t)row * 256 + colBlk * 128 + tn8;
        *(float4*)(Crow)     = o0;
        *(float4*)(Crow + 4) = o1;
    }
}

// ---------------------------------------------------------------------------
// fused_mid (grid 313, 32 rows/block):
//  phase0: LDS-staged CSR edge window -> mhT[d][m] = mean_e relu(u + ea*w); rmask
//  phase1: ts[32][128] = relu(xn + mhT @ M1)        (4x4 micro)
//  phase2: UX2[32][256] = ts @ WH + bias (+rm*v2)   (4x8 micro)
// ---------------------------------------------------------------------------
__global__ __launch_bounds__(256)
void fused_mid_kernel(const float* __restrict__ UX, const float* __restrict__ wlast,
                      const float* __restrict__ eas, const int* __restrict__ eoff,
                      const int* __restrict__ cnt,
                      const float* __restrict__ Mmat, const float* __restrict__ WH,
                      const float* __restrict__ bu2, const float* __restrict__ bx2,
                      const float* __restrict__ v2,
                      float* __restrict__ UX2, int M) {
    __shared__ float mhT[128][36];
    __shared__ float ts[32][132];
    __shared__ float Bs[16][264];
    __shared__ float ebuf[1536];
    __shared__ float rmask[32];
    int rowBase = blockIdx.x * 32;
    int tid = threadIdx.x;

    // ---- phase 0 ----
    {
        int d = tid & 127, sub = tid >> 7;
        float w = wlast[d];
        float uu[16], sum[16];
        int es[16], ec[16];
#pragma unroll
        for (int it = 0; it < 16; ++it) {
            int n  = rowBase + it * 2 + sub;
            int nc = (n < M) ? n : M - 1;
            ec[it] = cnt[nc];
            es[it] = eoff[nc];
            uu[it] = UX[(size_t)nc * 256 + d];
            sum[it] = 0.f;
            if (d == 0) rmask[it * 2 + sub] = (ec[it] > 0) ? 1.f : 0.f;
        }
        int ebase = eoff[rowBase];
        int eend  = (rowBase + 32 < M) ? eoff[rowBase + 32] : E_EDGES;
        for (int w0 = ebase; w0 < eend; w0 += 1536) {
            int wlen = min(1536, eend - w0);
            __syncthreads();
            for (int q = tid; q < wlen; q += 256) ebuf[q] = eas[w0 + q];
            __syncthreads();
#pragma unroll
            for (int it = 0; it < 16; ++it) {
                int lo = max(es[it], w0), hi = min(es[it] + ec[it], w0 + wlen);
                for (int e = lo; e < hi; ++e)
                    sum[it] += fmaxf(fmaf(ebuf[e - w0], w, uu[it]), 0.f);
            }
        }
#pragma unroll
        for (int it = 0; it < 16; ++it)
            mhT[d][it * 2 + sub] = (ec[it] > 0) ? sum[it] / (float)ec[it] : 0.f;
    }
    __syncthreads();

    // ---- phase 1: ts = relu(xn + mhT @ Mmat) ----
    {
        int tm = tid >> 5, tn = tid & 31;
        float acc[4][4] = {};
        for (int k0 = 0; k0 < 128; k0 += 16) {
#pragma unroll
            for (int t2 = 0; t2 < 2; ++t2) {
                int f2 = (tid << 1) | t2;
                int kr = f2 >> 5, c4 = (f2 & 31) << 2;
                *(float4*)&Bs[kr][c4] = *(const float4*)(Mmat + (size_t)(k0 + kr) * 128 + c4);
            }
            __syncthreads();
#pragma unroll
            for (int k = 0; k < 16; ++k) {
                float4 a = *(const float4*)&mhT[k0 + k][tm << 2];
                float4 b = *(const float4*)&Bs[k][tn << 2];
                acc[0][0] = fmaf(a.x, b.x, acc[0][0]); acc[0][1] = fmaf(a.x, b.y, acc[0][1]);
                acc[0][2] = fmaf(a.x, b.z, acc[0][2]); acc[0][3] = fmaf(a.x, b.w, acc[0][3]);
                acc[1][0] = fmaf(a.y, b.x, acc[1][0]); acc[1][1] = fmaf(a.y, b.y, acc[1][1]);
                acc[1][2] = fmaf(a.y, b.z, acc[1][2]); acc[1][3] = fmaf(a.y, b.w, acc[1][3]);
                acc[2][0] = fmaf(a.z, b.x, acc[2][0]); acc[2][1] = fmaf(a.z, b.y, acc[2][1]);
                acc[2][2] = fmaf(a.z, b.z, acc[2][2]); acc[2][3] = fmaf(a.z, b.w, acc[2][3]);
                acc[3][0] = fmaf(a.w, b.x, acc[3][0]); acc[3][1] = fmaf(a.w, b.y, acc[3][1]);
                acc[3][2] = fmaf(a.w, b.z, acc[3][2]); acc[3][3] = fmaf(a.w, b.w, acc[3][3]);
            }
            __syncthreads();
        }
#pragma unroll
        for (int i = 0; i < 4; ++i) {
            int row = rowBase + (tm << 2) + i;
            int rc  = (row < M) ? row : M - 1;
#pragma unroll
            for (int j = 0; j < 4; ++j) {
                int col = (tn << 2) + j;
                float v = acc[i][j] + UX[(size_t)rc * 256 + 128 + col];
                ts[(tm << 2) + i][col] = fmaxf(v, 0.f);
            }
        }
    }

    // ---- phase 2: UX2 = ts @ WH + bias ----
    {
        int tm = tid >> 5, tn = tid & 31;   // rows 4*tm, cols 8*tn
        float acc[4][8] = {};
        for (int k0 = 0; k0 < 128; k0 += 16) {
#pragma unroll
            for (int q = 0; q < 4; ++q) {
                int slot = (q << 8) + tid;
                int kr = slot >> 6, c4 = (slot & 63) << 2;
                *(float4*)&Bs[kr][c4] = *(const float4*)(WH + (size_t)(k0 + kr) * 256 + c4);
            }
            __syncthreads();   // also orders ts writes (phase1) before ts reads
#pragma unroll
            for (int k = 0; k < 16; ++k) {
                float4 b0 = *(const float4*)&Bs[k][tn << 3];
                float4 b1 = *(const float4*)&Bs[k][(tn << 3) + 4];
                float br[8] = {b0.x, b0.y, b0.z, b0.w, b1.x, b1.y, b1.z, b1.w};
#pragma unroll
                for (int i = 0; i < 4; ++i) {
                    float a = ts[(tm << 2) + i][k0 + k];
#pragma unroll
                    for (int j = 0; j < 8; ++j)
                        acc[i][j] = fmaf(a, br[j], acc[i][j]);
                }
            }
            __syncthreads();
        }
        bool half = (tn >= 16);
        const float* bias = half ? bx2 : bu2;
#pragma unroll
        for (int i = 0; i < 4; ++i) {
            int row = rowBase + (tm << 2) + i;
            if (row >= M) continue;
            float rm = rmask[(tm << 2) + i];
            float4 o0, o1;
            float* po0 = (float*)&o0; float* po1 = (float*)&o1;
#pragma unroll
            for (int j = 0; j < 4; ++j) {
                int gcol0 = (tn << 3) + j, gcol1 = (tn << 3) + 4 + j;
                int cj0 = gcol0 & 127, cj1 = gcol1 & 127;
                float v0 = acc[i][j] + bias[cj0];
                float v1s = acc[i][4 + j] + bias[cj1];
                if (half) { v0 = fmaf(rm, v2[cj0], v0); v1s = fmaf(rm, v2[cj1], v1s); }
                po0[j] = v0; po1[j] = v1s;
            }
            float* orow = UX2 + (size_t)row * 256 + (tn << 3);
            *(float4*)(orow)     = o0;
            *(float4*)(orow + 4) = o1;
        }
    }
}

// ---------------------------------------------------------------------------
// fused_last: phase0 (LDS-staged edges) + z2 = relu(xn2 + mh@M2) + proj
// ---------------------------------------------------------------------------
__global__ __launch_bounds__(256)
void fused_last_kernel(const float* __restrict__ UX2, const float* __restrict__ wlast,
                       const float* __restrict__ eas, const int* __restrict__ eoff,
                       const int* __restrict__ cnt,
                       const float* __restrict__ Mmat,
                       const float* __restrict__ w2, const float* __restrict__ b2,
                       float* __restrict__ proj, int M) {
    __shared__ float mhT[128][36];
    __shared__ float Bs[16][132];
    __shared__ float ebuf[1536];
    int rowBase = blockIdx.x * 32;
    int tid = threadIdx.x;

    {
        int d = tid & 127, sub = tid >> 7;
        float w = wlast[d];
        float uu[16], sum[16];
        int es[16], ec[16];
#pragma unroll
        for (int it = 0; it < 16; ++it) {
            int n  = rowBase + it * 2 + sub;
            int nc = (n < M) ? n : M - 1;
            ec[it] = cnt[nc];
            es[it] = eoff[nc];
            uu[it] = UX2[(size_t)nc * 256 + d];
            sum[it] = 0.f;
        }
        int ebase = eoff[rowBase];
        int eend  = (rowBase + 32 < M) ? eoff[rowBase + 32] : E_EDGES;
        for (int w0 = ebase; w0 < eend; w0 += 1536) {
            int wlen = min(1536, eend - w0);
            __syncthreads();
            for (int q = tid; q < wlen; q += 256) ebuf[q] = eas[w0 + q];
            __syncthreads();
#pragma unroll
            for (int it = 0; it < 16; ++it) {
                int lo = max(es[it], w0), hi = min(es[it] + ec[it], w0 + wlen);
                for (int e = lo; e < hi; ++e)
                    sum[it] += fmaxf(fmaf(ebuf[e - w0], w, uu[it]), 0.f);
            }
        }
#pragma unroll
        for (int it = 0; it < 16; ++it)
            mhT[d][it * 2 + sub] = (ec[it] > 0) ? sum[it] / (float)ec[it] : 0.f;
    }
    __syncthreads();

    int tm = tid >> 5, tn = tid & 31;
    float acc[4][4] = {};
    for (int k0 = 0; k0 < 128; k0 += 16) {
#pragma unroll
        for (int t2 = 0; t2 < 2; ++t2) {
            int f2 = (tid << 1) | t2;
            int kr = f2 >> 5, c4 = (f2 & 31) << 2;
            *(float4*)&Bs[kr][c4] = *(const float4*)(Mmat + (size_t)(k0 + kr) * 128 + c4);
        }
        __syncthreads();
#pragma unroll
        for (int k = 0; k < 16; ++k) {
            float4 a = *(const float4*)&mhT[k0 + k][tm << 2];
            float4 b = *(const float4*)&Bs[k][tn << 2];
            acc[0][0] = fmaf(a.x, b.x, acc[0][0]); acc[0][1] = fmaf(a.x, b.y, acc[0][1]);
            acc[0][2] = fmaf(a.x, b.z, acc[0][2]); acc[0][3] = fmaf(a.x, b.w, acc[0][3]);
            acc[1][0] = fmaf(a.y, b.x, acc[1][0]); acc[1][1] = fmaf(a.y, b.y, acc[1][1]);
            acc[1][2] = fmaf(a.y, b.z, acc[1][2]); acc[1][3] = fmaf(a.y, b.w, acc[1][3]);
            acc[2][0] = fmaf(a.z, b.x, acc[2][0]); acc[2][1] = fmaf(a.z, b.y, acc[2][1]);
            acc[2][2] = fmaf(a.z, b.z, acc[2][2]); acc[2][3] = fmaf(a.z, b.w, acc[2][3]);
            acc[3][0] = fmaf(a.w, b.x, acc[3][0]); acc[3][1] = fmaf(a.w, b.y, acc[3][1]);
            acc[3][2] = fmaf(a.w, b.z, acc[3][2]); acc[3][3] = fmaf(a.w, b.w, acc[3][3]);
        }
        __syncthreads();
    }

    float p0[4] = {}, p1[4] = {};
#pragma unroll
    for (int i = 0; i < 4; ++i) {
        int row = rowBase + (tm << 2) + i;
        int rc  = (row < M) ? row : M - 1;
#pragma unroll
        for (int j = 0; j < 4; ++j) {
            int col = (tn << 2) + j;
            float t = fmaxf(acc[i][j] + UX2[(size_t)rc * 256 + 128 + col], 0.f);
            p0[i] = fmaf(t, w2[col * 2],     p0[i]);
            p1[i] = fmaf(t, w2[col * 2 + 1], p1[i]);
        }
    }
#pragma unroll
    for (int i = 0; i < 4; ++i) {
        for (int off = 16; off > 0; off >>= 1) {
            p0[i] += __shfl_xor(p0[i], off, 64);
            p1[i] += __shfl_xor(p1[i], off, 64);
        }
    }
    if (tn == 0) {
#pragma unroll
        for (int i = 0; i < 4; ++i) {
            int row = rowBase + (tm << 2) + i;
            if (row < M) {
                proj[row * 2]     = p0[i] + b2[0];
                proj[row * 2 + 1] = p1[i] + b2[1];
            }
        }
    }
}

__global__ void dist_kernel(const float* __restrict__ proj, const int* __restrict__ idxs,
                            float* __restrict__ out, int e) {
    int i = blockIdx.x * blockDim.x + threadIdx.x;
    if (i >= e) return;
    int n = i / KNB;
    int m = idxs[i];
    float dx = proj[2 * n] - proj[2 * m];
    float dy = proj[2 * n + 1] - proj[2 * m + 1];
    out[i] = dx * dx + dy * dy;
}

// ---------------------------------------------------------------------------
extern "C" void kernel_launch(void* const* d_in, const int* in_sizes, int n_in,
                              void* d_out, int out_size, void* d_ws, size_t ws_size,
                              hipStream_t stream) {
    (void)in_sizes; (void)n_in; (void)out_size; (void)ws_size;
    const float* x    = (const float*)d_in[0];
    const float* eatt = (const float*)d_in[1];
    const int*   idxs = (const int*)d_in[2];
    const float* mw1  = (const float*)d_in[3];
    const float* mb1  = (const float*)d_in[4];
    const float* mw2  = (const float*)d_in[5];
    const float* mb2  = (const float*)d_in[6];
    const float* nw1  = (const float*)d_in[7];
    const float* nb1  = (const float*)d_in[8];
    const float* nw2  = (const float*)d_in[9];
    const float* nb2  = (const float*)d_in[10];
    const float* m2w1 = (const float*)d_in[11];
    const float* m2b1 = (const float*)d_in[12];
    const float* m2w2 = (const float*)d_in[13];
    const float* m2b2 = (const float*)d_in[14];
    const float* n2w1 = (const float*)d_in[15];
    const float* n2b1 = (const float*)d_in[16];
    const float* n2w2 = (const float*)d_in[17];
    const float* n2b2 = (const float*)d_in[18];
    float* out = (float*)d_out;

    float* fws   = (float*)d_ws;
    float* UX1   = fws;                   // 10000*256
    float* UX2   = fws + 2560000;         // 10000*256
    float* proj  = fws + 5120000;         // 10000*2
    float* maskv = fws + 5140000;         // 10000
    float* eas   = fws + 5150016;         // 150000
    float* M1    = fws + 5300016;         // 128*128
    float* M2    = fws + 5316400;         // 128*128
    float* WH    = fws + 5332784;         // 128*256
    float* v1    = fws + 5365552;         // 128
    float* v2    = fws + 5365680;         // 128
    float* bu2   = fws + 5365808;         // 128
    float* bx2   = fws + 5365936;         // 128
    int*   cnt   = (int*)(fws + 5366064);
    int*   fill  = cnt + N_NODES;
    int*   eoff  = fill + N_NODES;

    hipMemsetAsync(cnt, 0, 2 * N_NODES * sizeof(int), stream);   // cnt + fill

    int egrid = (E_EDGES + 255) / 256;
    count_kernel<<<egrid, 256, 0, stream>>>(idxs, cnt, E_EDGES);
    scan_kernel<<<1, 1024, 0, stream>>>(cnt, eoff, maskv, N_NODES);
    fill_kernel<<<egrid, 256, 0, stream>>>(idxs, eatt, eoff, fill, eas, E_EDGES);

    fold_kernel<<<40, 256, 0, stream>>>(mw2, mb2, nw1, nb2, nw2,
                                        m2w1, m2b1, m2w2, m2b2, n2w1, n2b1,
                                        M1, M2, WH, v1, v2, bu2, bx2);

    // UX1 = [ x@mw1+mb1 | x@nw1+nb1+maskv*v1 ]  (79 row-blocks x 2 col-blocks)
    gemm784_kernel<<<158, 256, 0, stream>>>(x, mw1, nw1, mb1, nb1, v1, maskv,
                                            UX1, N_NODES);

    // layer 1 msg-mean + z1 + layer-2 input projection
    fused_mid_kernel<<<313, 256, 0, stream>>>(UX1, mw1 + 784 * 128, eas, eoff, cnt,
                                              M1, WH, bu2, bx2, v2, UX2, N_NODES);

    // layer 2 msg-mean + z2 + proj
    fused_last_kernel<<<313, 256, 0, stream>>>(UX2, m2w1 + 128 * 128, eas, eoff, cnt,
                                               M2, n2w2, n2b2, proj, N_NODES);

    dist_kernel<<<egrid, 256, 0, stream>>>(proj, idxs, out, E_EDGES);
}